// Round 7
// baseline (133.413 us; speedup 1.0000x reference)
//
#include <hip/hip_runtime.h>

typedef unsigned short u16;
typedef unsigned int u32;
typedef unsigned long long u64;
typedef __attribute__((ext_vector_type(8))) short short8;
typedef __attribute__((ext_vector_type(4))) float f32x4;

#define NN 8192
#define FIN 512
#define FO 200
#define FP 208
#define CO 20
#define SCAP 128
#define ALPHA 0.2f
#define GEMM_BLOCKS 256
#define STRIPE_BLOCKS (NN * 4)

__device__ __forceinline__ u16 f2bf(float f){
  union { float f; unsigned u; } c; c.f = f;
  unsigned u = c.u;
  return (u16)((u + 0x7fffu + ((u >> 16) & 1u)) >> 16);
}
__device__ __forceinline__ float bf2f(u16 s){
  union { unsigned u; float f; } c; c.u = ((unsigned)s) << 16;
  return c.f;
}

// ========== K1 fused: [0,256) gemm | [256, 256+32768) stripe-compact ========
__launch_bounds__(256)
__global__ void k_main(const float* __restrict__ support, const float* __restrict__ x,
                       const float* __restrict__ W, const float* __restrict__ a1,
                       const float* __restrict__ a2, u16* __restrict__ hb,
                       float* __restrict__ f1, float* __restrict__ f2,
                       int* __restrict__ cnts, u16* __restrict__ idxg,
                       float* __restrict__ valg){
  int tid = threadIdx.x, lane = tid & 63, wid = tid >> 6;
  int bid = blockIdx.x;

  if (bid >= GEMM_BLOCKS) {
    // ---- compact one 2048-element stripe: one 8KB burst, short tail ----
    int sb = bid - GEMM_BLOCKS;
    int row = sb >> 2, s = sb & 3;
    __shared__ int wsum[4];
    const f32x4* row4 = (const f32x4*)(support + (size_t)row * NN) + s * 512 + wid * 128 + lane;
    f32x4 v0 = __builtin_nontemporal_load(row4);
    f32x4 v1 = __builtin_nontemporal_load(row4 + 64);
    int wcnt = 0;
    #pragma unroll
    for (int c = 0; c < 4; c++) wcnt += __popcll(__ballot(v0[c] > 0.f));
    #pragma unroll
    for (int c = 0; c < 4; c++) wcnt += __popcll(__ballot(v1[c] > 0.f));
    if (lane == 0) wsum[wid] = wcnt;
    __syncthreads();
    int wbase = 0;
    for (int w = 0; w < wid; w++) wbase += wsum[w];
    int total = wsum[0] + wsum[1] + wsum[2] + wsum[3];
    u16* ig = idxg + (size_t)row * 512 + s * SCAP;
    float* vg = valg + (size_t)row * 512 + s * SCAP;
    u64 lanemask = (1ull << lane) - 1ull;
    int base = wbase;
    int colbase = s * 2048 + wid * 512 + lane * 4;
    #pragma unroll
    for (int k = 0; k < 2; k++) {
      #pragma unroll
      for (int c = 0; c < 4; c++) {
        float val = k ? v1[c] : v0[c];
        bool p = val > 0.f;
        u64 mk = __ballot(p);
        if (p) {
          int pos = base + __popcll(mk & lanemask);
          if (pos < SCAP) {
            ig[pos] = (u16)(colbase + k * 256 + c);
            vg[pos] = val;
          }
        }
        base += __popcll(mk);
      }
    }
    if (tid == 0) cnts[4 * row + s] = min(total, SCAP);
    return;
  }

  // ---- gemm role: h = bf16(x) @ bf16(W), f1/f2 epilogue (R6, unchanged) ----
  __shared__ __align__(16) u16 As[32 * 32];
  __shared__ __align__(16) u16 Bs[FP * 32];
  __shared__ float a1s[FP], a2s[FP];
  __shared__ float fpart[2][4][32];
  int rb = bid * 32;
  if (tid < FP) {
    a1s[tid] = (tid < FO) ? a1[tid] : 0.f;
    a2s[tid] = (tid < FO) ? a2[tid] : 0.f;
  }
  if (tid < 256) Bs[(200 + (tid >> 5)) * 32 + (tid & 31)] = 0;
  int r2 = 0, c4 = 0;
  if (tid < 200) { r2 = tid / 50; c4 = tid % 50; }
  f32x4 acc[7];
  #pragma unroll
  for (int n = 0; n < 7; n++) acc[n] = (f32x4){0.f, 0.f, 0.f, 0.f};
  for (int k0 = 0; k0 < FIN; k0 += 32) {
    __syncthreads();
    {
      int r = tid >> 3, kk = (tid & 7) * 4;
      const f32x4* xp = (const f32x4*)(x + (size_t)(rb + r) * FIN + k0 + kk);
      f32x4 xv = *xp;
      ushort4 hv;
      hv.x = f2bf(xv[0]); hv.y = f2bf(xv[1]); hv.z = f2bf(xv[2]); hv.w = f2bf(xv[3]);
      *(ushort4*)&As[r * 32 + (((kk >> 3) ^ ((r >> 1) & 3)) * 8) + (kk & 7)] = hv;
    }
    if (tid < 200) {
      #pragma unroll
      for (int g2 = 0; g2 < 8; g2++) {
        int row = g2 * 4 + r2;
        f32x4 wv = *(const f32x4*)(W + (size_t)(k0 + row) * FO + c4 * 4);
        int grp = (row >> 3), within = (row & 7);
        #pragma unroll
        for (int j = 0; j < 4; j++) {
          int col = c4 * 4 + j;
          Bs[col * 32 + ((grp ^ ((col >> 1) & 3)) * 8) + within] = f2bf(wv[j]);
        }
      }
    }
    __syncthreads();
    int jr = lane >> 4;
    #pragma unroll
    for (int n = 0; n < 7; n++) {
      int t = wid + 4 * n;
      if (t < 26) {
        int rt = t / 13, ct = t % 13;
        int lr = rt * 16 + (lane & 15);
        short8 af = *(const short8*)&As[lr * 32 + (jr ^ ((lr >> 1) & 3)) * 8];
        int col = ct * 16 + (lane & 15);
        short8 bfv = *(const short8*)&Bs[col * 32 + (jr ^ ((col >> 1) & 3)) * 8];
        acc[n] = __builtin_amdgcn_mfma_f32_16x16x32_bf16(af, bfv, acc[n], 0, 0, 0);
      }
    }
  }
  float f1a[2][4] = {{0.f,0.f,0.f,0.f},{0.f,0.f,0.f,0.f}};
  float f2a[2][4] = {{0.f,0.f,0.f,0.f},{0.f,0.f,0.f,0.f}};
  #pragma unroll
  for (int n = 0; n < 7; n++) {
    int t = wid + 4 * n;
    if (t < 26) {
      int rt = t / 13, ct = t % 13;
      int col = ct * 16 + (lane & 15);
      float av1 = a1s[col], av2 = a2s[col];
      int rbase = rb + rt * 16 + 4 * (lane >> 4);
      #pragma unroll
      for (int q = 0; q < 4; q++) {
        float hv = acc[n][q];
        if (col < FO) hb[(size_t)(rbase + q) * FO + col] = f2bf(hv);
        f1a[rt][q] = fmaf(hv, av1, f1a[rt][q]);
        f2a[rt][q] = fmaf(hv, av2, f2a[rt][q]);
      }
    }
  }
  #pragma unroll
  for (int rt = 0; rt < 2; rt++) {
    #pragma unroll
    for (int q = 0; q < 4; q++) {
      float v1 = f1a[rt][q], v2 = f2a[rt][q];
      #pragma unroll
      for (int o = 1; o < 16; o <<= 1) { v1 += __shfl_xor(v1, o); v2 += __shfl_xor(v2, o); }
      if ((lane & 15) == 0) {
        int row = rt * 16 + 4 * (lane >> 4) + q;
        fpart[0][wid][row] = v1;
        fpart[1][wid][row] = v2;
      }
    }
  }
  __syncthreads();
  if (tid < 32) {
    f1[rb + tid] = fpart[0][0][tid] + fpart[0][1][tid] + fpart[0][2][tid] + fpart[0][3][tid];
    f2[rb + tid] = fpart[1][0][tid] + fpart[1][1][tid] + fpart[1][2][tid] + fpart[1][3][tid];
  }
}

// ---------------- K2: softmax + h'=elu(att@h) + g = h'@W0 (fused) -----------
__launch_bounds__(128)
__global__ void k_gather(const int* __restrict__ cnts, const u16* __restrict__ idxg,
                         const float* __restrict__ f1, const float* __restrict__ f2,
                         const u16* __restrict__ hb, const float* __restrict__ W0,
                         float* __restrict__ g){
  int i = blockIdx.x;
  int tid = threadIdx.x, lane = tid & 63, wid = tid >> 6;
  __shared__ int s_j[512];
  __shared__ float s_w[512];
  __shared__ float s_red[4];
  __shared__ float s_hp[FO];
  __shared__ float s_part[120];
  int4 cc = *(const int4*)&cnts[4 * i];
  int o1 = cc.x, o2 = o1 + cc.y, o3 = o2 + cc.z, nnz = o3 + cc.w;
  const u16* ig = idxg + (size_t)i * 512;
  for (int t = tid; t < cc.x; t += 128) s_j[t]      = ig[t];
  for (int t = tid; t < cc.y; t += 128) s_j[o1 + t] = ig[SCAP + t];
  for (int t = tid; t < cc.z; t += 128) s_j[o2 + t] = ig[2 * SCAP + t];
  for (int t = tid; t < cc.w; t += 128) s_j[o3 + t] = ig[3 * SCAP + t];
  __syncthreads();
  float fi = f1[i];
  float ev[4];
  #pragma unroll
  for (int q = 0; q < 4; q++) {
    int t = tid + 128 * q;
    ev[q] = -1e30f;
    if (t < nnz) { float e = fi + f2[s_j[t]]; ev[q] = e > 0.f ? e : ALPHA * e; }
  }
  float m = fmaxf(fmaxf(ev[0], ev[1]), fmaxf(ev[2], ev[3]));
  #pragma unroll
  for (int o = 32; o; o >>= 1) m = fmaxf(m, __shfl_xor(m, o));
  if (lane == 0) s_red[wid] = m;
  __syncthreads();
  m = fmaxf(s_red[0], s_red[1]);
  float pv[4];
  float s = 0.f;
  #pragma unroll
  for (int q = 0; q < 4; q++) {
    int t = tid + 128 * q;
    pv[q] = (t < nnz) ? __expf(ev[q] - m) : 0.f;
    s += pv[q];
  }
  #pragma unroll
  for (int o = 32; o; o >>= 1) s += __shfl_xor(s, o);
  if (lane == 0) s_red[2 + wid] = s;
  __syncthreads();
  float rs = 1.0f / (s_red[2] + s_red[3]);
  #pragma unroll
  for (int q = 0; q < 4; q++) {
    int t = tid + 128 * q;
    if (t < nnz) s_w[t] = pv[q] * rs;
  }
  __syncthreads();
  if (tid < 100) {
    float ax = 0.f, ay = 0.f;
    int jj = 0;
    for (; jj + 8 <= nnz; jj += 8) {
      #pragma unroll
      for (int q = 0; q < 8; q++) {
        int j = s_j[jj + q];
        float w = s_w[jj + q];
        u32 hv = *(const u32*)&hb[(size_t)j * FO + 2 * tid];
        ax = fmaf(w, bf2f((u16)(hv & 0xffffu)), ax);
        ay = fmaf(w, bf2f((u16)(hv >> 16)), ay);
      }
    }
    for (; jj < nnz; jj++) {
      int j = s_j[jj];
      float w = s_w[jj];
      u32 hv = *(const u32*)&hb[(size_t)j * FO + 2 * tid];
      ax = fmaf(w, bf2f((u16)(hv & 0xffffu)), ax);
      ay = fmaf(w, bf2f((u16)(hv >> 16)), ay);
    }
    s_hp[2 * tid]     = ax > 0.f ? ax : expm1f(ax);
    s_hp[2 * tid + 1] = ay > 0.f ? ay : expm1f(ay);
  }
  __syncthreads();
  if (tid < 120) {
    int c = tid % 20, dg = tid / 20;
    float acc = 0.f;
    for (int d = dg; d < FO; d += 6)
      acc = fmaf(s_hp[d], W0[d * CO + c], acc);
    s_part[tid] = acc;
  }
  __syncthreads();
  if (tid < 20) {
    float a = s_part[tid] + s_part[tid + 20] + s_part[tid + 40]
            + s_part[tid + 60] + s_part[tid + 80] + s_part[tid + 100];
    g[(size_t)i * CO + tid] = a;
  }
}

// ---------------- K3: out = support @ g  (sparse rep, LDS-staged) ------------
__launch_bounds__(256)
__global__ void k_out(const int* __restrict__ cnts, const u16* __restrict__ idxg,
                      const float* __restrict__ valg, const float* __restrict__ g,
                      float* __restrict__ out){
  int tid = threadIdx.x, lane = tid & 63, wid = tid >> 6;
  int i = blockIdx.x * 4 + wid;
  __shared__ int s_j[4][512];
  __shared__ float s_w[4][512];
  int4 cc = *(const int4*)&cnts[4 * i];
  int o1 = cc.x, o2 = o1 + cc.y, o3 = o2 + cc.z, nnz = o3 + cc.w;
  const u16* ig = idxg + (size_t)i * 512;
  const float* vg = valg + (size_t)i * 512;
  for (int t = lane; t < cc.x; t += 64) { s_j[wid][t]      = ig[t];            s_w[wid][t]      = vg[t]; }
  for (int t = lane; t < cc.y; t += 64) { s_j[wid][o1 + t] = ig[SCAP + t];     s_w[wid][o1 + t] = vg[SCAP + t]; }
  for (int t = lane; t < cc.z; t += 64) { s_j[wid][o2 + t] = ig[2 * SCAP + t]; s_w[wid][o2 + t] = vg[2 * SCAP + t]; }
  for (int t = lane; t < cc.w; t += 64) { s_j[wid][o3 + t] = ig[3 * SCAP + t]; s_w[wid][o3 + t] = vg[3 * SCAP + t]; }
  __syncthreads();
  int c = lane % 20, grp = lane / 20;
  float acc = 0.f;
  if (grp < 3) {
    for (int jj = grp; jj < nnz; jj += 3)
      acc = fmaf(s_w[wid][jj], g[(size_t)s_j[wid][jj] * CO + c], acc);
  }
  float b1 = __shfl(acc, lane + 20);
  float b2 = __shfl(acc, lane + 40);
  if (lane < 20) out[(size_t)i * CO + lane] = acc + b1 + b2;
}

extern "C" void kernel_launch(void* const* d_in, const int* in_sizes, int n_in,
                              void* d_out, int out_size, void* d_ws, size_t ws_size,
                              hipStream_t stream) {
  (void)in_sizes; (void)n_in; (void)out_size; (void)ws_size;
  const float* x       = (const float*)d_in[0];
  const float* support = (const float*)d_in[1];
  const float* W       = (const float*)d_in[2];
  const float* a1      = (const float*)d_in[3];
  const float* a2      = (const float*)d_in[4];
  const float* W0      = (const float*)d_in[5];
  char* ws = (char*)d_ws;
  float* f1   = (float*)(ws + 0);          // 8192*4       = 32768
  float* f2   = (float*)(ws + 32768);      // 8192*4       = 32768
  u16*   hb   = (u16*)  (ws + 65536);      // 8192*200*2   = 3276800
  float* g    = (float*)(ws + 3342336);    // 8192*20*4    = 655360
  int*   cnts = (int*)  (ws + 3997696);    // 8192*4*4     = 131072
  u16*   idxg = (u16*)  (ws + 4128768);    // 8192*512*2   = 8388608
  float* valg = (float*)(ws + 12517376);   // 8192*512*4   = 16777216
  float* outp = (float*)d_out;

  k_main  <<<GEMM_BLOCKS + STRIPE_BLOCKS, 256, 0, stream>>>(support, x, W, a1, a2,
                                                            hb, f1, f2, cnts, idxg, valg);
  k_gather<<<NN,     128, 0, stream>>>(cnts, idxg, f1, f2, hb, W0, g);
  k_out   <<<NN / 4, 256, 0, stream>>>(cnts, idxg, valg, g, outp);
}